// Round 1
// baseline (779.135 us; speedup 1.0000x reference)
//
#include <hip/hip_runtime.h>

constexpr int S    = 256;  // window length
constexpr int D    = 32;   // d_model
constexpr int NH   = 4;
constexpr int DH   = 8;
constexpr int DFF  = 64;
constexpr int NL   = 4;
constexpr int IND  = 58;
constexpr int HOUT = 25;

__device__ __forceinline__ float dot32(const float* __restrict__ w, const float* v) {
  float a0 = 0.f, a1 = 0.f, a2 = 0.f, a3 = 0.f;
#pragma unroll
  for (int i = 0; i < 8; ++i) {
    a0 = fmaf(v[i],      w[i],      a0);
    a1 = fmaf(v[8 + i],  w[8 + i],  a1);
    a2 = fmaf(v[16 + i], w[16 + i], a2);
    a3 = fmaf(v[24 + i], w[24 + i], a3);
  }
  return (a0 + a1) + (a2 + a3);
}

__device__ __forceinline__ float dot64(const float* __restrict__ w, const float* v) {
  float a0 = 0.f, a1 = 0.f, a2 = 0.f, a3 = 0.f;
#pragma unroll
  for (int i = 0; i < 16; ++i) {
    a0 = fmaf(v[i],      w[i],      a0);
    a1 = fmaf(v[16 + i], w[16 + i], a1);
    a2 = fmaf(v[32 + i], w[32 + i], a2);
    a3 = fmaf(v[48 + i], w[48 + i], a3);
  }
  return (a0 + a1) + (a2 + a3);
}

__device__ __forceinline__ float dot58(const float* __restrict__ w, const float* v) {
  float a0 = 0.f, a1 = 0.f;
#pragma unroll
  for (int i = 0; i < 29; ++i) {
    a0 = fmaf(v[2 * i],     w[2 * i],     a0);
    a1 = fmaf(v[2 * i + 1], w[2 * i + 1], a1);
  }
  return a0 + a1;
}

__device__ __forceinline__ void lnorm(float* h, const float* __restrict__ g,
                                      const float* __restrict__ b) {
  float s = 0.f;
#pragma unroll
  for (int d = 0; d < D; ++d) s += h[d];
  const float m = s * (1.0f / D);
  float v = 0.f;
#pragma unroll
  for (int d = 0; d < D; ++d) { float c = h[d] - m; v = fmaf(c, c, v); }
  const float inv = rsqrtf(v * (1.0f / D) + 1e-5f);
#pragma unroll
  for (int d = 0; d < D; ++d) h[d] = (h[d] - m) * inv * g[d] + b[d];
}

// One block per 256-token window; thread = token. h[] in registers end-to-end.
// K/V in LDS as [token][64] = exactly 64 KB -> 2 blocks/CU, grid 512 = 2/CU.
__global__ void __launch_bounds__(256, 2)
spai_fused(const float* __restrict__ x,    const int*   __restrict__ layers,
           const float* __restrict__ fpw,  const float* __restrict__ fpb,
           const float* __restrict__ lemb, const float* __restrict__ fB,
           const float* __restrict__ ipw,  const float* __restrict__ ipb,
           const float* __restrict__ opw,  const float* __restrict__ opb,
           const float* __restrict__ ln1g, const float* __restrict__ ln1b,
           const float* __restrict__ w1,   const float* __restrict__ b1,
           const float* __restrict__ w2,   const float* __restrict__ b2,
           const float* __restrict__ ln2g, const float* __restrict__ ln2b,
           const float* __restrict__ nog,  const float* __restrict__ nob,
           const float* __restrict__ hw,   const float* __restrict__ hb,
           float* __restrict__ out)
{
  __shared__ float smem[S * 2 * D];  // 16384 floats = 64 KB
  const int w   = blockIdx.x;
  const int tid = threadIdx.x;
  const int t   = w * S + tid;  // global token id

  // ---- stage x window into LDS (coalesced), then read this token's row ----
  const float* xw = x + (size_t)w * S * IND;
  for (int i = tid; i < S * IND; i += S) smem[i] = xw[i];
  __syncthreads();
  float xr[IND];
#pragma unroll
  for (int i = 0; i < IND; ++i) xr[i] = smem[tid * IND + i];

  // ---- embedding: x @ fpw^T + fpb + layer_embed[layer] + fourier PE ----
  float h[D];
  {
    const int lay = layers[t];
    const float* le = lemb + lay * D;
    float pe[D];
#pragma unroll
    for (int k = 0; k < 16; ++k) {
      // proj = 2*pi * (pos @ fourier_B); fB is (3,16) row-major
      float pr = 6.2831853071795864f *
                 (xr[0] * fB[k] + xr[1] * fB[16 + k] + xr[2] * fB[32 + k]);
      float sv, cv;
      sincosf(pr, &sv, &cv);
      pe[k]      = sv;
      pe[16 + k] = cv;
    }
#pragma unroll
    for (int d = 0; d < D; ++d)
      h[d] = dot58(fpw + d * IND, xr) + fpb[d] + le[d] + pe[d];
  }

  // ---- transformer layers ----
  for (int l = 0; l < NL; ++l) {
    const float* Wi = ipw + l * (3 * D) * D;
    const float* Bi = ipb + l * (3 * D);
    float q[D], kv[2 * D];
#pragma unroll
    for (int o = 0; o < D; ++o)
      q[o] = (dot32(Wi + o * D, h) + Bi[o]) * 0.35355339059327373f; // fold 1/sqrt(dh)
#pragma unroll
    for (int o = 0; o < 2 * D; ++o)
      kv[o] = dot32(Wi + (D + o) * D, h) + Bi[D + o];

    __syncthreads();  // all prior smem readers done
    {
      float4* row = (float4*)(smem + tid * (2 * D));
#pragma unroll
      for (int i = 0; i < 16; ++i)
        row[i] = make_float4(kv[4 * i], kv[4 * i + 1], kv[4 * i + 2], kv[4 * i + 3]);
    }
    __syncthreads();

    // ---- attention: max-free online softmax (scores are O(1) here) ----
    float acc[D], lsum[NH];
#pragma unroll
    for (int d = 0; d < D; ++d) acc[d] = 0.f;
#pragma unroll
    for (int hh = 0; hh < NH; ++hh) lsum[hh] = 0.f;

    for (int j = 0; j < S; ++j) {
      const float4* kr = (const float4*)(smem + j * (2 * D));  // uniform -> broadcast
      float kk[D];
#pragma unroll
      for (int i = 0; i < 8; ++i) {
        float4 a = kr[i];
        kk[4 * i] = a.x; kk[4 * i + 1] = a.y; kk[4 * i + 2] = a.z; kk[4 * i + 3] = a.w;
      }
      float e[NH];
#pragma unroll
      for (int hh = 0; hh < NH; ++hh) {
        float s = 0.f;
#pragma unroll
        for (int d2 = 0; d2 < DH; ++d2)
          s = fmaf(q[hh * DH + d2], kk[hh * DH + d2], s);
        e[hh] = __expf(s);
        lsum[hh] += e[hh];
      }
      float vv[D];
#pragma unroll
      for (int i = 0; i < 8; ++i) {
        float4 a = kr[8 + i];
        vv[4 * i] = a.x; vv[4 * i + 1] = a.y; vv[4 * i + 2] = a.z; vv[4 * i + 3] = a.w;
      }
#pragma unroll
      for (int hh = 0; hh < NH; ++hh) {
#pragma unroll
        for (int d2 = 0; d2 < DH; ++d2)
          acc[hh * DH + d2] = fmaf(e[hh], vv[hh * DH + d2], acc[hh * DH + d2]);
      }
    }

#pragma unroll
    for (int hh = 0; hh < NH; ++hh) {
      const float inv = 1.0f / lsum[hh];
#pragma unroll
      for (int d2 = 0; d2 < DH; ++d2) acc[hh * DH + d2] *= inv;
    }

    // ---- out-proj + residual + LN1 ----
    const float* Wo = opw + l * D * D;
    const float* Bo = opb + l * D;
    float o2[D];
#pragma unroll
    for (int d = 0; d < D; ++d) o2[d] = dot32(Wo + d * D, acc) + Bo[d];
#pragma unroll
    for (int d = 0; d < D; ++d) h[d] += o2[d];
    lnorm(h, ln1g + l * D, ln1b + l * D);

    // ---- FF: gelu(h @ w1^T + b1) @ w2^T + b2, residual, LN2 ----
    const float* Wa = w1 + l * DFF * D;
    const float* Ba = b1 + l * DFF;
    float tt[DFF];
#pragma unroll
    for (int j = 0; j < DFF; ++j) {
      float tj = dot32(Wa + j * D, h) + Ba[j];
      tt[j] = 0.5f * tj * (1.0f + erff(tj * 0.70710678118654752f));
    }
    const float* Wb = w2 + l * D * DFF;
    const float* Bb = b2 + l * D;
#pragma unroll
    for (int d = 0; d < D; ++d) h[d] += dot64(Wb + d * DFF, tt) + Bb[d];
    lnorm(h, ln2g + l * D, ln2b + l * D);
  }

  // ---- final LN + head (staged through LDS for coalesced stores) ----
  lnorm(h, nog, nob);
  __syncthreads();  // last layer's attention readers done before overwrite
#pragma unroll
  for (int o = 0; o < HOUT; ++o)
    smem[tid * HOUT + o] = dot32(hw + o * D, h) + hb[o];
  __syncthreads();
  float* ow = out + (size_t)w * S * HOUT;
  for (int i = tid; i < S * HOUT; i += S) ow[i] = smem[i];
}

extern "C" void kernel_launch(void* const* d_in, const int* in_sizes, int n_in,
                              void* d_out, int out_size, void* d_ws, size_t ws_size,
                              hipStream_t stream) {
  const float* x    = (const float*)d_in[0];
  const int*   lays = (const int*)  d_in[1];
  const float* fpw  = (const float*)d_in[2];
  const float* fpb  = (const float*)d_in[3];
  const float* lemb = (const float*)d_in[4];
  const float* fB   = (const float*)d_in[5];
  const float* ipw  = (const float*)d_in[6];
  const float* ipb  = (const float*)d_in[7];
  const float* opw  = (const float*)d_in[8];
  const float* opb  = (const float*)d_in[9];
  const float* ln1g = (const float*)d_in[10];
  const float* ln1b = (const float*)d_in[11];
  const float* w1   = (const float*)d_in[12];
  const float* b1   = (const float*)d_in[13];
  const float* w2   = (const float*)d_in[14];
  const float* b2   = (const float*)d_in[15];
  const float* ln2g = (const float*)d_in[16];
  const float* ln2b = (const float*)d_in[17];
  const float* nog  = (const float*)d_in[18];
  const float* nob  = (const float*)d_in[19];
  const float* hw   = (const float*)d_in[20];
  const float* hb   = (const float*)d_in[21];
  float* out = (float*)d_out;

  const int nwin = in_sizes[0] / (S * IND);  // = B*N/WINDOW = 512
  spai_fused<<<nwin, S, 0, stream>>>(x, lays, fpw, fpb, lemb, fB, ipw, ipb,
                                     opw, opb, ln1g, ln1b, w1, b1, w2, b2,
                                     ln2g, ln2b, nog, nob, hw, hb, out);
}